// Round 1
// baseline (288.327 us; speedup 1.0000x reference)
//
#include <hip/hip_runtime.h>
#include <hip/hip_bf16.h>

#define NN 10000
#define KK 32
#define DDIRIN 10
#define DDIR 64
#define DD 128          // D_DIST == D_DIST_IN == D_ATOM == 128

typedef short bf16x8 __attribute__((ext_vector_type(8)));
typedef float f32x4  __attribute__((ext_vector_type(4)));
typedef float f32x2  __attribute__((ext_vector_type(2)));

__device__ __forceinline__ float silu_f(float x) { return x / (1.0f + __expf(-x)); }

// packed f32x2 -> bf16x2 (RNE) -> raw shorts
__device__ __forceinline__ ushort2 pk_bf16(float a, float b) {
    __hip_bfloat162 h = __float22bfloat162_rn(float2{a, b});
    union { __hip_bfloat162 h; ushort2 u; } v; v.h = h;
    return v.u;
}

// Single fused kernel: 4 nodes per block (256 threads, 4 waves).
//  - cols 0..128  : bf16 MFMA GEMM of edist @ dW, silu+masked-mean epilogue
//  - cols 128..512: per-wave segment reduction (sender dir recomputed, no ws)
// edist is streamed with nontemporal loads so dW/semb/nde stay L2-resident.
__global__ __launch_bounds__(256, 2) void fused_kernel(
    const int*   __restrict__ an,      // [N]
    const float* __restrict__ nde,     // [N,10]
    const float* __restrict__ edist,   // [N,32,128]
    const int*   __restrict__ nl,      // [N,32]
    const int*   __restrict__ nmask,   // [N,32]
    const float* __restrict__ semb,    // [100,128]
    const float* __restrict__ temb,    // [100,128]
    const float* __restrict__ sW, const float* __restrict__ sb,
    const float* __restrict__ tW, const float* __restrict__ tb,
    const float* __restrict__ dW,      // [128,128]
    const float* __restrict__ db,      // [128]
    float* __restrict__ out)           // [N,512]
{
    const int tid  = threadIdx.x;
    const int wid  = tid >> 6;       // wave -> seg node n0+wid; gemm cols [32*wid, 32*wid+32)
    const int lane = tid & 63;
    const int l15  = lane & 15;
    const int quad = lane >> 4;
    const int n0   = blockIdx.x * 4;
    const int n    = n0 + wid;

    __shared__ __align__(16) short s_E[128 * 128];   // 32 KB bf16, swizzled
    __shared__ float s_cnt[4];

    // ---- neighbor ballot-compaction, register-only (no LDS round-trip) ----
    int j = 0, aj = 0; bool act = false;
    if (lane < KK) {
        j   = nl[n * KK + lane];
        act = (nmask[n * KK + lane] != 0);
    }
    unsigned long long bits = __ballot(act);
    int cnt = (int)__popcll(bits);
    if (act) aj = an[j];                 // gather atomic numbers in parallel
    if (lane == 0) s_cnt[wid] = (float)cnt;

    // ---- B fragments: dW cvt'd to bf16, in registers (L2-served re-read) ----
    bf16x8 bfrag[2][4];
    float  bias[2];
#pragma unroll
    for (int c2 = 0; c2 < 2; ++c2) {
        int ncol = (2 * wid + c2) * 16 + l15;
        bias[c2] = db[ncol];
#pragma unroll
        for (int t = 0; t < 4; ++t) {
            bf16x8 v;
#pragma unroll
            for (int j2 = 0; j2 < 4; ++j2) {
                int k0 = t * 32 + quad * 8 + 2 * j2;
                ushort2 u = pk_bf16(dW[k0 * DD + ncol], dW[(k0 + 1) * DD + ncol]);
                v[2 * j2]     = (short)u.x;
                v[2 * j2 + 1] = (short)u.y;
            }
            bfrag[c2][t] = v;
        }
    }

    // ---- Stage 4 edist rows (64 KB f32) -> bf16 LDS, zeroing masked rows. ----
    // Nontemporal: edist is stream-once; keep it out of L2 so dW/semb/nde survive.
    {
        const f32x4* E4 = reinterpret_cast<const f32x4*>(edist + (size_t)n0 * (KK * DD));
        const int* nm = nmask + n0 * KK;
#pragma unroll
        for (int i = 0; i < 8; ++i) {
            int f0  = 2 * tid + 512 * i;
            int row = f0 >> 5;
            f32x4 a = __builtin_nontemporal_load(&E4[f0]);
            f32x4 b = __builtin_nontemporal_load(&E4[f0 + 1]);
            ushort2 u0 = pk_bf16(a[0], a[1]), u1 = pk_bf16(a[2], a[3]);
            ushort2 u2 = pk_bf16(b[0], b[1]), u3 = pk_bf16(b[2], b[3]);
            bf16x8 v;
            v[0] = (short)u0.x; v[1] = (short)u0.y; v[2] = (short)u1.x; v[3] = (short)u1.y;
            v[4] = (short)u2.x; v[5] = (short)u2.y; v[6] = (short)u3.x; v[7] = (short)u3.y;
            bf16x8 z;
#pragma unroll
            for (int q = 0; q < 8; ++q) z[q] = 0;
            v = (nm[row] != 0) ? v : z;
            int kb = tid & 15;
            int sw = kb ^ (row & 7);
            *reinterpret_cast<bf16x8*>(&s_E[row * 128 + sw * 8]) = v;
        }
    }
    __syncthreads();   // the ONLY barrier

    // ---- MFMA: C[128 rows x 128 cols]; wave owns 32 cols, all 8 row-tiles. ----
    f32x4 acc[8][2];
#pragma unroll
    for (int rt = 0; rt < 8; ++rt)
#pragma unroll
        for (int c2 = 0; c2 < 2; ++c2)
#pragma unroll
            for (int g = 0; g < 4; ++g) acc[rt][c2][g] = 0.0f;

#pragma unroll
    for (int rt = 0; rt < 8; ++rt) {
        bf16x8 af[4];
        int r = rt * 16 + l15;
#pragma unroll
        for (int t = 0; t < 4; ++t) {
            int kb = (4 * t + quad) ^ (l15 & 7);
            af[t] = *reinterpret_cast<const bf16x8*>(&s_E[r * 128 + kb * 8]);
        }
#pragma unroll
        for (int t = 0; t < 4; ++t) {
            acc[rt][0] = __builtin_amdgcn_mfma_f32_16x16x32_bf16(af[t], bfrag[0][t], acc[rt][0], 0, 0, 0);
            acc[rt][1] = __builtin_amdgcn_mfma_f32_16x16x32_bf16(af[t], bfrag[1][t], acc[rt][1], 0, 0, 0);
        }
    }

    // ---- GEMM epilogue (cols 0..128). D layout: col=l15, row=quad*4+reg (+16*rt).
    // Masked rows were zeroed: sum_masked silu = sum_all silu - (32-cnt)*silu(bias).
#pragma unroll
    for (int c2 = 0; c2 < 2; ++c2) {
        float sbv = silu_f(bias[c2]);
#pragma unroll
        for (int nd = 0; nd < 4; ++nd) {
            float p = 0.0f;
#pragma unroll
            for (int h = 0; h < 2; ++h) {
                int rt = 2 * nd + h;
#pragma unroll
                for (int g = 0; g < 4; ++g)
                    p += silu_f(acc[rt][c2][g] + bias[c2]);
            }
            p += __shfl_xor(p, 16);
            p += __shfl_xor(p, 32);
            if (quad == nd) {
                float c = s_cnt[nd];
                float val = (p - (32.0f - c) * sbv) / (c + 1e-5f);
                __builtin_nontemporal_store(
                    val, &out[(size_t)(n0 + nd) * 512 + (2 * wid + c2) * 16 + l15]);
            }
        }
    }

    // ---- Segment section (cols 128..512), one wave per node, no extra barrier. ----
    {
        const float invv  = 1.0f / ((float)cnt + 1e-5f);
        const float scale = (float)cnt * invv;
        float* outn = out + (size_t)n * 512;

        // hoist sender-dir weights: lane owns output dim `lane`
        float sw_r[DDIRIN];
#pragma unroll
        for (int q = 0; q < DDIRIN; ++q) sw_r[q] = sW[q * DDIR + lane];
        const float sbv = sb[lane];

        float sdir = 0.0f, sa0 = 0.0f, sa1 = 0.0f;
        unsigned long long rem = bits;
        for (int i = 0; i < cnt; ++i) {
            int src = __builtin_ctzll(rem); rem &= rem - 1ull;
            int jj = __shfl(j, src);
            int ja = __shfl(aj, src);
            // sender dir: recompute silu(nde[jj] @ sW + sb) — 10 FMA/lane
            const f32x2* x2 = reinterpret_cast<const f32x2*>(nde + (size_t)jj * DDIRIN);
            float a = sbv;
#pragma unroll
            for (int q = 0; q < 5; ++q) {
                f32x2 xv = x2[q];
                a = fmaf(xv[0], sw_r[2 * q], a);
                a = fmaf(xv[1], sw_r[2 * q + 1], a);
            }
            sdir += silu_f(a);
            // sender atom: full 512B row per wave as float2/lane
            f32x2 e = reinterpret_cast<const f32x2*>(semb + (size_t)ja * DD)[lane];
            sa0 += e[0]; sa1 += e[1];
        }
        __builtin_nontemporal_store(sdir * invv, &outn[128 + lane]);
        f32x2 sa = {sa0 * invv, sa1 * invv};
        __builtin_nontemporal_store(sa, reinterpret_cast<f32x2*>(&outn[192 + 2 * lane]));

        // recv dir: silu(nde[n] @ tW + tb) * cnt/(cnt+eps)
        {
            const f32x2* x2 = reinterpret_cast<const f32x2*>(nde + (size_t)n * DDIRIN);
            float a = tb[lane];
#pragma unroll
            for (int q = 0; q < 5; ++q) {
                f32x2 xv = x2[q];
                a = fmaf(xv[0], tW[(2 * q) * DDIR + lane], a);
                a = fmaf(xv[1], tW[(2 * q + 1) * DDIR + lane], a);
            }
            __builtin_nontemporal_store(silu_f(a) * scale, &outn[320 + lane]);
        }

        // recv atom
        {
            int ann = an[n];
            f32x2 r = reinterpret_cast<const f32x2*>(temb + (size_t)ann * DD)[lane];
            f32x2 rv = {r[0] * scale, r[1] * scale};
            __builtin_nontemporal_store(rv, reinterpret_cast<f32x2*>(&outn[384 + 2 * lane]));
        }
    }
}

extern "C" void kernel_launch(void* const* d_in, const int* in_sizes, int n_in,
                              void* d_out, int out_size, void* d_ws, size_t ws_size,
                              hipStream_t stream) {
    const int*   an    = (const int*)  d_in[0];
    const float* nde   = (const float*)d_in[1];
    const float* edist = (const float*)d_in[2];
    const int*   nl    = (const int*)  d_in[3];
    const int*   nmask = (const int*)  d_in[4];
    const float* semb  = (const float*)d_in[5];
    const float* temb  = (const float*)d_in[6];
    const float* sW    = (const float*)d_in[7];
    const float* sb    = (const float*)d_in[8];
    const float* tW    = (const float*)d_in[9];
    const float* tb    = (const float*)d_in[10];
    const float* dW    = (const float*)d_in[11];
    const float* db    = (const float*)d_in[12];
    float* out = (float*)d_out;

    fused_kernel<<<NN / 4, 256, 0, stream>>>(
        an, nde, edist, nl, nmask, semb, temb, sW, sb, tW, tb, dW, db, out);
}